// Round 5
// baseline (449.548 us; speedup 1.0000x reference)
//
#include <hip/hip_runtime.h>
#include <hip/hip_bf16.h>

#define B_ 8
#define N_ 2048
#define D_ 128
#define NW_ (N_ / 32)   // mask words per row = 64

typedef __bf16 bf16_t;
typedef __bf16 v8bf __attribute__((ext_vector_type(8)));
typedef float  v4f  __attribute__((ext_vector_type(4)));

// ---------------------------------------------------------------------------
// k_prep: WT[o][i] = (bf16)Ww[i][o]; AT[o][i] = (bf16)Aw[i][o].
// ---------------------------------------------------------------------------
__global__ __launch_bounds__(256) void k_prep(
    const float* __restrict__ Ww, const float* __restrict__ Aw,
    bf16_t* __restrict__ WT, bf16_t* __restrict__ AT)
{
    int idx = blockIdx.x * 256 + threadIdx.x;   // 0..16383
    int o = idx >> 7, i = idx & 127;
    WT[idx] = (bf16_t)Ww[i * D_ + o];
    AT[idx] = (bf16_t)Aw[i * D_ + o];
}

// ---------------------------------------------------------------------------
// k_mask: pack adj>0 into bits. mk[b][n][m/32], bit (m&31). Exact: adj is
// {0.0,1.0}. Streams 134 MB once at dense BW.
// ---------------------------------------------------------------------------
__global__ __launch_bounds__(256) void k_mask(
    const float* __restrict__ adj, unsigned int* __restrict__ mk)
{
    int w = blockIdx.x * 256 + threadIdx.x;      // 0 .. 8*2048*64-1
    const float* src = adj + (size_t)w * 32;
    unsigned int bits = 0;
#pragma unroll
    for (int k = 0; k < 8; ++k) {
        float4 f = *(const float4*)(src + k * 4);
        bits |= (f.x > 0.f ? 1u : 0u) << (k * 4 + 0);
        bits |= (f.y > 0.f ? 1u : 0u) << (k * 4 + 1);
        bits |= (f.z > 0.f ? 1u : 0u) << (k * 4 + 2);
        bits |= (f.w > 0.f ? 1u : 0u) << (k * 4 + 3);
    }
    mk[w] = bits;
}

// ---------------------------------------------------------------------------
// k_hg (MFMA): h = x@W + b; g = h@A.  Block = 64 rows, 4 waves x 16 rows.
// ---------------------------------------------------------------------------
__global__ __launch_bounds__(256) void k_hg(
    const float* __restrict__ x, const float* __restrict__ Wb,
    const bf16_t* __restrict__ WT, const bf16_t* __restrict__ AT,
    bf16_t* __restrict__ hb, bf16_t* __restrict__ gb)
{
    int wave = threadIdx.x >> 6;
    int lane = threadIdx.x & 63;
    int q = lane >> 4;
    int c = lane & 15;
    int nrow0 = blockIdx.x * 64 + wave * 16;    // global flat row (b*N+n)

    __shared__ float pw_all[4][16][132];
    float (*pw)[132] = pw_all[wave];

    v8bf ax[4];
#pragma unroll
    for (int kc = 0; kc < 4; ++kc) {
        const float* src = x + (size_t)(nrow0 + c) * D_ + kc * 32 + q * 8;
        float4 f0 = *(const float4*)src;
        float4 f1 = *(const float4*)(src + 4);
        v8bf a;
        a[0]=(bf16_t)f0.x; a[1]=(bf16_t)f0.y; a[2]=(bf16_t)f0.z; a[3]=(bf16_t)f0.w;
        a[4]=(bf16_t)f1.x; a[5]=(bf16_t)f1.y; a[6]=(bf16_t)f1.z; a[7]=(bf16_t)f1.w;
        ax[kc] = a;
    }

#pragma unroll
    for (int ct = 0; ct < 8; ++ct) {
        float bias = Wb[ct * 16 + c];
        v4f acc = {bias, bias, bias, bias};
#pragma unroll
        for (int kc = 0; kc < 4; ++kc) {
            v8bf bw = *(const v8bf*)(WT + (size_t)(ct * 16 + c) * D_ + kc * 32 + q * 8);
            acc = __builtin_amdgcn_mfma_f32_16x16x32_bf16(ax[kc], bw, acc, 0, 0, 0);
        }
#pragma unroll
        for (int r = 0; r < 4; ++r) pw[q * 4 + r][ct * 16 + c] = acc[r];
    }
    __builtin_amdgcn_wave_barrier();

    v8bf ahf[4];
#pragma unroll
    for (int kc = 0; kc < 4; ++kc) {
        v4f p0 = *(const v4f*)&pw[c][kc * 32 + q * 8];
        v4f p1 = *(const v4f*)&pw[c][kc * 32 + q * 8 + 4];
        v8bf a;
#pragma unroll
        for (int j = 0; j < 4; ++j) { a[j] = (bf16_t)p0[j]; a[j+4] = (bf16_t)p1[j]; }
        ahf[kc] = a;
    }
    {
        int row = lane >> 2, seg = lane & 3;
#pragma unroll
        for (int v = 0; v < 4; ++v) {
            v8bf hv;
#pragma unroll
            for (int j = 0; j < 8; ++j) hv[j] = (bf16_t)pw[row][seg * 32 + v * 8 + j];
            *(v8bf*)(hb + (size_t)(nrow0 + row) * D_ + seg * 32 + v * 8) = hv;
        }
    }
    __builtin_amdgcn_wave_barrier();

#pragma unroll
    for (int ct = 0; ct < 8; ++ct) {
        v4f acc = {0.f, 0.f, 0.f, 0.f};
#pragma unroll
        for (int kc = 0; kc < 4; ++kc) {
            v8bf bw = *(const v8bf*)(AT + (size_t)(ct * 16 + c) * D_ + kc * 32 + q * 8);
            acc = __builtin_amdgcn_mfma_f32_16x16x32_bf16(ahf[kc], bw, acc, 0, 0, 0);
        }
#pragma unroll
        for (int r = 0; r < 4; ++r) pw[q * 4 + r][ct * 16 + c] = acc[r];
    }
    __builtin_amdgcn_wave_barrier();
    {
        int row = lane >> 2, seg = lane & 3;
#pragma unroll
        for (int v = 0; v < 4; ++v) {
            v8bf gv;
#pragma unroll
            for (int j = 0; j < 8; ++j) gv[j] = (bf16_t)pw[row][seg * 32 + v * 8 + j];
            *(v8bf*)(gb + (size_t)(nrow0 + row) * D_ + seg * 32 + v * 8) = gv;
        }
    }
}

// ---------------------------------------------------------------------------
// k_cs (pass 1): cs[b][m] = sum_n mask[n,m]*exp(e[n,m]).  No P storage.
// grid 512: b(8) x mblk(64 x 32m).  4 waves; wave w streams n = w*16 + j*64.
// Persistent B (m-side, 32 rows h+g) = 64 VGPR; per chunk: 12 loads, 16
// MFMAs, 8 exps; cs kept in regs, 2 atomics/wave at the end (4096 total).
// Small footprint -> 4 waves/SIMD residency (the r0-r4 k_att was stuck at 2).
// ---------------------------------------------------------------------------
__global__ __launch_bounds__(256) void k_cs(
    const bf16_t* __restrict__ hb, const bf16_t* __restrict__ gb,
    const unsigned int* __restrict__ mk, float* __restrict__ colsum)
{
    int bid = blockIdx.x;          // 0..511
    int b = bid & 7;
    int mblk = bid >> 3;           // 0..63
    int wave = threadIdx.x >> 6;
    int lane = threadIdx.x & 63;
    int q = lane >> 4, c = lane & 15;
    int m0 = mblk * 32;
    const size_t hgoff = (size_t)b * N_ * D_;
    const unsigned int* mkb = mk + (size_t)b * N_ * NW_;

    v8bf bh[2][4], bg2[2][4];
#pragma unroll
    for (int ms = 0; ms < 2; ++ms)
#pragma unroll
        for (int kc = 0; kc < 4; ++kc) {
            size_t off = hgoff + (size_t)(m0 + ms * 16 + c) * D_ + kc * 32 + q * 8;
            bh[ms][kc]  = *(const v8bf*)(hb + off);
            bg2[ms][kc] = *(const v8bf*)(gb + off);
        }

    float cs0 = 0.f, cs1 = 0.f;
    for (int j = 0; j < 32; ++j) {
        int n0 = j * 64 + wave * 16;
        v8bf ah[4], ag[4];
#pragma unroll
        for (int kc = 0; kc < 4; ++kc) {
            size_t off = hgoff + (size_t)(n0 + c) * D_ + kc * 32 + q * 8;
            ah[kc] = *(const v8bf*)(hb + off);
            ag[kc] = *(const v8bf*)(gb + off);
        }
        unsigned int mw[4];
#pragma unroll
        for (int r = 0; r < 4; ++r)
            mw[r] = mkb[(size_t)(n0 + q * 4 + r) * NW_ + mblk];
        v4f e0 = {0.f,0.f,0.f,0.f}, e1 = {0.f,0.f,0.f,0.f};
#pragma unroll
        for (int kc = 0; kc < 4; ++kc) {
            e0 = __builtin_amdgcn_mfma_f32_16x16x32_bf16(ag[kc], bh[0][kc], e0, 0, 0, 0);
            e0 = __builtin_amdgcn_mfma_f32_16x16x32_bf16(ah[kc], bg2[0][kc], e0, 0, 0, 0);
            e1 = __builtin_amdgcn_mfma_f32_16x16x32_bf16(ag[kc], bh[1][kc], e1, 0, 0, 0);
            e1 = __builtin_amdgcn_mfma_f32_16x16x32_bf16(ah[kc], bg2[1][kc], e1, 0, 0, 0);
        }
#pragma unroll
        for (int r = 0; r < 4; ++r) {
            cs0 += ((mw[r] >> c) & 1u) ? __expf(e0[r]) : 0.f;
            cs1 += ((mw[r] >> (16 + c)) & 1u) ? __expf(e1[r]) : 0.f;
        }
    }
    cs0 += __shfl_xor(cs0, 16);  cs0 += __shfl_xor(cs0, 32);
    cs1 += __shfl_xor(cs1, 16);  cs1 += __shfl_xor(cs1, 32);
    if (lane < 16) {
        atomicAdd(&colsum[b * N_ + m0 + lane], cs0);
        atomicAdd(&colsum[b * N_ + m0 + 16 + lane], cs1);
    }
}

// ---------------------------------------------------------------------------
// k_scaleT: hbTs[b][d][m] = h[b][m][d] * inv(colsum[b][m]).
// ---------------------------------------------------------------------------
__global__ __launch_bounds__(256) void k_scaleT(
    const bf16_t* __restrict__ hb, const float* __restrict__ colsum,
    bf16_t* __restrict__ hbTs)
{
    int bid = blockIdx.x;
    int b = bid >> 6;
    int rem = bid & 63;
    int nblk = rem >> 1;
    int dblk = rem & 1;
    int tid = threadIdx.x;
    __shared__ bf16_t sm[64][72];
    __shared__ float sinv[64];
    int n0 = nblk * 64, d0 = dblk * 64;
    int r = tid >> 3, cg = tid & 7;
#pragma unroll
    for (int rr = 0; rr < 2; ++rr) {
        int row = r + rr * 32;
        *(v8bf*)&sm[row][cg * 8] =
            *(const v8bf*)(hb + (size_t)(b * N_ + n0 + row) * D_ + d0 + cg * 8);
    }
    if (tid < 64) {
        float s = colsum[b * N_ + n0 + tid];
        sinv[tid] = (s > 0.f) ? 1.f / s : 0.f;
    }
    __syncthreads();
#pragma unroll
    for (int rr = 0; rr < 2; ++rr) {
        int dr = r + rr * 32;
        v8bf v;
#pragma unroll
        for (int jj = 0; jj < 8; ++jj)
            v[jj] = (bf16_t)((float)sm[cg * 8 + jj][dr] * sinv[cg * 8 + jj]);
        *(v8bf*)(hbTs + (size_t)(b * D_ + d0 + dr) * N_ + n0 + cg * 8) = v;
    }
}

// ---------------------------------------------------------------------------
// k_pv (pass 2): h' = P~ @ hbTs with E recomputed on the fly (bit-identical
// to k_cs: same fragments, same MFMA order), P~ round-tripped through a
// 4.6 KB double-buffered LDS tile (replaces the 129 MB Pt global round
// trip), fused relu+gate epilogue.  grid 512: b(8) x nblk(64 x 32n).
// E phase: wave = (nsub = w>>1, mhalf = w&1) computes E[16n x 32m].
// PV phase: wave = d-quarter; A-frags = ds_read_b128 of P, B = hbTs rows.
// ONE barrier per chunk: E(ch+1) writes buf[ch+1 & 1] which PV(ch) never
// reads; E(ch+2)'s reuse of buf[ch&1] is fenced by barrier(ch+1).
// ---------------------------------------------------------------------------
__global__ __launch_bounds__(256) void k_pv(
    const bf16_t* __restrict__ hb, const bf16_t* __restrict__ gb,
    const unsigned int* __restrict__ mk, const bf16_t* __restrict__ hbTs,
    const float* __restrict__ x, const float* __restrict__ gw,
    const float* __restrict__ gbias, float* __restrict__ out)
{
    int bid = blockIdx.x;          // 0..511
    int b = bid & 7;
    int nblk = bid >> 3;           // 0..63
    int tid = threadIdx.x;
    int wave = tid >> 6;
    int lane = tid & 63;
    int q = lane >> 4, c = lane & 15;
    int nbase = nblk * 32;
    int nsub = wave >> 1;          // E-phase n-subtile (0..1)
    int mh = wave & 1;             // E-phase m-half (0..1)

    __shared__ bf16_t P[2][32][72];
    __shared__ float hp[32][132];

    const size_t hgoff = (size_t)b * N_ * D_;
    const unsigned int* mkb = mk + (size_t)b * N_ * NW_;
    const bf16_t* hTb = hbTs + (size_t)b * D_ * N_;

    // persistent A-frags: this block's n-rows (16 per wave-pair) = 32 VGPR
    v8bf pah[4], pag[4];
#pragma unroll
    for (int kc = 0; kc < 4; ++kc) {
        size_t off = hgoff + (size_t)(nbase + nsub * 16 + c) * D_ + kc * 32 + q * 8;
        pah[kc] = *(const v8bf*)(hb + off);
        pag[kc] = *(const v8bf*)(gb + off);
    }

    v4f acc[2][2];
#pragma unroll
    for (int ns = 0; ns < 2; ++ns)
#pragma unroll
        for (int dt = 0; dt < 2; ++dt) acc[ns][dt] = (v4f){0.f, 0.f, 0.f, 0.f};

    for (int ch = 0; ch < 32; ++ch) {
        int mc = ch * 64;
        int cur = ch & 1;
        // ---- E phase: E[16n x 32m] for this wave's (nsub, mh)
        v8bf bh[2][4], bg2[2][4];
#pragma unroll
        for (int ms = 0; ms < 2; ++ms)
#pragma unroll
            for (int kc = 0; kc < 4; ++kc) {
                size_t off = hgoff + (size_t)(mc + mh * 32 + ms * 16 + c) * D_ + kc * 32 + q * 8;
                bh[ms][kc]  = *(const v8bf*)(hb + off);
                bg2[ms][kc] = *(const v8bf*)(gb + off);
            }
        unsigned int mw[4];
#pragma unroll
        for (int r = 0; r < 4; ++r)
            mw[r] = mkb[(size_t)(nbase + nsub * 16 + q * 4 + r) * NW_ + (mc >> 5) + mh];
        v4f e0 = {0.f,0.f,0.f,0.f}, e1 = {0.f,0.f,0.f,0.f};
#pragma unroll
        for (int kc = 0; kc < 4; ++kc) {
            e0 = __builtin_amdgcn_mfma_f32_16x16x32_bf16(pag[kc], bh[0][kc], e0, 0, 0, 0);
            e0 = __builtin_amdgcn_mfma_f32_16x16x32_bf16(pah[kc], bg2[0][kc], e0, 0, 0, 0);
            e1 = __builtin_amdgcn_mfma_f32_16x16x32_bf16(pag[kc], bh[1][kc], e1, 0, 0, 0);
            e1 = __builtin_amdgcn_mfma_f32_16x16x32_bf16(pah[kc], bg2[1][kc], e1, 0, 0, 0);
        }
#pragma unroll
        for (int r = 0; r < 4; ++r) {
            float p0 = ((mw[r] >> c) & 1u) ? __expf(e0[r]) : 0.f;
            float p1 = ((mw[r] >> (16 + c)) & 1u) ? __expf(e1[r]) : 0.f;
            P[cur][nsub * 16 + q * 4 + r][mh * 32 + c]      = (bf16_t)p0;
            P[cur][nsub * 16 + q * 4 + r][mh * 32 + 16 + c] = (bf16_t)p1;
        }
        __syncthreads();
        // ---- PV phase: wave = d-quarter (wave*32 .. +32)
#pragma unroll
        for (int k2 = 0; k2 < 2; ++k2) {
            v8bf pa0 = *(const v8bf*)&P[cur][c][k2 * 32 + q * 8];
            v8bf pa1 = *(const v8bf*)&P[cur][16 + c][k2 * 32 + q * 8];
            v8bf vt0 = *(const v8bf*)(hTb + (size_t)(wave * 32 + c) * N_ + mc + k2 * 32 + q * 8);
            v8bf vt1 = *(const v8bf*)(hTb + (size_t)(wave * 32 + 16 + c) * N_ + mc + k2 * 32 + q * 8);
            acc[0][0] = __builtin_amdgcn_mfma_f32_16x16x32_bf16(pa0, vt0, acc[0][0], 0, 0, 0);
            acc[0][1] = __builtin_amdgcn_mfma_f32_16x16x32_bf16(pa0, vt1, acc[0][1], 0, 0, 0);
            acc[1][0] = __builtin_amdgcn_mfma_f32_16x16x32_bf16(pa1, vt0, acc[1][0], 0, 0, 0);
            acc[1][1] = __builtin_amdgcn_mfma_f32_16x16x32_bf16(pa1, vt1, acc[1][1], 0, 0, 0);
        }
    }

    // write h' (pre-relu) to LDS: rows 0..31, cols = this wave's d-quarter
#pragma unroll
    for (int ns = 0; ns < 2; ++ns)
#pragma unroll
        for (int dt = 0; dt < 2; ++dt)
#pragma unroll
            for (int r = 0; r < 4; ++r)
                hp[ns * 16 + q * 4 + r][wave * 32 + dt * 16 + c] = acc[ns][dt][r];
    __syncthreads();

    // fused gate epilogue: 256 thr = 32 rows x 8 segs x 16 d
    int row = tid >> 3;
    int seg = tid & 7;
    size_t g = (size_t)b * N_ + nbase + row;
    const float* xr = x + g * D_ + seg * 16;
    float xv[16], hv[16];
#pragma unroll
    for (int j = 0; j < 16; j += 4) {
        float4 f = *(const float4*)(xr + j);
        xv[j] = f.x; xv[j+1] = f.y; xv[j+2] = f.z; xv[j+3] = f.w;
    }
#pragma unroll
    for (int j = 0; j < 16; ++j) hv[j] = fmaxf(hp[row][seg * 16 + j], 0.f);
    float part = 0.f;
#pragma unroll
    for (int j = 0; j < 16; ++j)
        part += xv[j] * gw[seg * 16 + j] + hv[j] * gw[D_ + seg * 16 + j];
    part += __shfl_xor(part, 1);
    part += __shfl_xor(part, 2);
    part += __shfl_xor(part, 4);
    float coeff = 1.f / (1.f + __expf(-(part + gbias[0])));
    float* orow = out + g * D_ + seg * 16;
#pragma unroll
    for (int j = 0; j < 16; j += 4) {
        float4 o;
        o.x = coeff * xv[j]   + (1.f - coeff) * hv[j];
        o.y = coeff * xv[j+1] + (1.f - coeff) * hv[j+1];
        o.z = coeff * xv[j+2] + (1.f - coeff) * hv[j+2];
        o.w = coeff * xv[j+3] + (1.f - coeff) * hv[j+3];
        *(float4*)(orow + j) = o;
    }
}

// ---------------------------------------------------------------------------
extern "C" void kernel_launch(void* const* d_in, const int* in_sizes, int n_in,
                              void* d_out, int out_size, void* d_ws, size_t ws_size,
                              hipStream_t stream)
{
    const float* x     = (const float*)d_in[0];
    const float* adj   = (const float*)d_in[1];
    const float* Ww    = (const float*)d_in[2];
    const float* Wb    = (const float*)d_in[3];
    const float* Aw    = (const float*)d_in[4];
    const float* gw    = (const float*)d_in[5];
    const float* gbias = (const float*)d_in[6];
    float* out = (float*)d_out;

    char* ws = (char*)d_ws;
    bf16_t* hb     = (bf16_t*)(ws);                          // 4 MB
    bf16_t* gb     = (bf16_t*)(ws + (4 << 20));              // 4 MB
    bf16_t* hbTs   = (bf16_t*)(ws + (8 << 20));              // 4 MB
    float*  colsum = (float*)(ws + (12 << 20));              // 64 KB
    unsigned int* mkw = (unsigned int*)(ws + (13 << 20));    // 4 MB
    bf16_t* WT     = (bf16_t*)(ws + (81 << 20));             // 32 KB
    bf16_t* AT     = (bf16_t*)(ws + (81 << 20) + (32 << 10));// 32 KB

    hipMemsetAsync(colsum, 0, B_ * N_ * sizeof(float), stream);
    k_prep<<<64, 256, 0, stream>>>(Ww, Aw, WT, AT);
    k_mask<<<B_ * N_ * NW_ / 256, 256, 0, stream>>>(adj, mkw);
    k_hg<<<B_ * N_ / 64, 256, 0, stream>>>(x, Wb, WT, AT, hb, gb);
    k_cs<<<512, 256, 0, stream>>>(hb, gb, mkw, colsum);
    k_scaleT<<<512, 256, 0, stream>>>(hb, colsum, hbTs);
    k_pv<<<512, 256, 0, stream>>>(hb, gb, mkw, hbTs, x, gw, gbias, out);
}

// Round 6
// 352.900 us; speedup vs baseline: 1.2739x; 1.2739x over previous
//
#include <hip/hip_runtime.h>
#include <hip/hip_bf16.h>

#define B_ 8
#define N_ 2048
#define D_ 128
#define NW_ (N_ / 32)   // mask words per row = 64

typedef __bf16 bf16_t;
typedef __bf16 v8bf __attribute__((ext_vector_type(8)));
typedef float  v4f  __attribute__((ext_vector_type(4)));

// ---------------------------------------------------------------------------
// k_prep: WT[o][i] = (bf16)Ww[i][o];  ST[o][i] = (bf16)(Aw[i][o]+Aw[o][i]).
// Symmetry trick: e + e^T = h A h^T + h A^T h^T = h (A+A^T) h^T, so with
// g = h@(A+A^T) the E-phase needs ONE product g.h^T instead of two.
// ---------------------------------------------------------------------------
__global__ __launch_bounds__(256) void k_prep(
    const float* __restrict__ Ww, const float* __restrict__ Aw,
    bf16_t* __restrict__ WT, bf16_t* __restrict__ ST)
{
    int idx = blockIdx.x * 256 + threadIdx.x;   // 0..16383
    int o = idx >> 7, i = idx & 127;
    WT[idx] = (bf16_t)Ww[i * D_ + o];
    ST[idx] = (bf16_t)(Aw[i * D_ + o] + Aw[o * D_ + i]);
}

// ---------------------------------------------------------------------------
// k_mask: pack adj>0 into bits. mk[b][n][m/32], bit (m&31). Exact (adj is
// {0.0,1.0}). Streams 134 MB once at dense BW.
// ---------------------------------------------------------------------------
__global__ __launch_bounds__(256) void k_mask(
    const float* __restrict__ adj, unsigned int* __restrict__ mk)
{
    int w = blockIdx.x * 256 + threadIdx.x;      // 0 .. 8*2048*64-1
    const float* src = adj + (size_t)w * 32;
    unsigned int bits = 0;
#pragma unroll
    for (int k = 0; k < 8; ++k) {
        float4 f = *(const float4*)(src + k * 4);
        bits |= (f.x > 0.f ? 1u : 0u) << (k * 4 + 0);
        bits |= (f.y > 0.f ? 1u : 0u) << (k * 4 + 1);
        bits |= (f.z > 0.f ? 1u : 0u) << (k * 4 + 2);
        bits |= (f.w > 0.f ? 1u : 0u) << (k * 4 + 3);
    }
    mk[w] = bits;
}

// ---------------------------------------------------------------------------
// k_hg (MFMA): h = x@W + b; g = h@S.  Block = 64 rows, 4 waves x 16 rows.
// ---------------------------------------------------------------------------
__global__ __launch_bounds__(256) void k_hg(
    const float* __restrict__ x, const float* __restrict__ Wb,
    const bf16_t* __restrict__ WT, const bf16_t* __restrict__ ST,
    bf16_t* __restrict__ hb, bf16_t* __restrict__ gb)
{
    int wave = threadIdx.x >> 6;
    int lane = threadIdx.x & 63;
    int q = lane >> 4;
    int c = lane & 15;
    int nrow0 = blockIdx.x * 64 + wave * 16;    // global flat row (b*N+n)

    __shared__ float pw_all[4][16][132];
    float (*pw)[132] = pw_all[wave];

    v8bf ax[4];
#pragma unroll
    for (int kc = 0; kc < 4; ++kc) {
        const float* src = x + (size_t)(nrow0 + c) * D_ + kc * 32 + q * 8;
        float4 f0 = *(const float4*)src;
        float4 f1 = *(const float4*)(src + 4);
        v8bf a;
        a[0]=(bf16_t)f0.x; a[1]=(bf16_t)f0.y; a[2]=(bf16_t)f0.z; a[3]=(bf16_t)f0.w;
        a[4]=(bf16_t)f1.x; a[5]=(bf16_t)f1.y; a[6]=(bf16_t)f1.z; a[7]=(bf16_t)f1.w;
        ax[kc] = a;
    }

#pragma unroll
    for (int ct = 0; ct < 8; ++ct) {
        float bias = Wb[ct * 16 + c];
        v4f acc = {bias, bias, bias, bias};
#pragma unroll
        for (int kc = 0; kc < 4; ++kc) {
            v8bf bw = *(const v8bf*)(WT + (size_t)(ct * 16 + c) * D_ + kc * 32 + q * 8);
            acc = __builtin_amdgcn_mfma_f32_16x16x32_bf16(ax[kc], bw, acc, 0, 0, 0);
        }
#pragma unroll
        for (int r = 0; r < 4; ++r) pw[q * 4 + r][ct * 16 + c] = acc[r];
    }
    __builtin_amdgcn_wave_barrier();

    v8bf ahf[4];
#pragma unroll
    for (int kc = 0; kc < 4; ++kc) {
        v4f p0 = *(const v4f*)&pw[c][kc * 32 + q * 8];
        v4f p1 = *(const v4f*)&pw[c][kc * 32 + q * 8 + 4];
        v8bf a;
#pragma unroll
        for (int j = 0; j < 4; ++j) { a[j] = (bf16_t)p0[j]; a[j+4] = (bf16_t)p1[j]; }
        ahf[kc] = a;
    }
    {
        int row = lane >> 2, seg = lane & 3;
#pragma unroll
        for (int v = 0; v < 4; ++v) {
            v8bf hv;
#pragma unroll
            for (int j = 0; j < 8; ++j) hv[j] = (bf16_t)pw[row][seg * 32 + v * 8 + j];
            *(v8bf*)(hb + (size_t)(nrow0 + row) * D_ + seg * 32 + v * 8) = hv;
        }
    }
    __builtin_amdgcn_wave_barrier();

#pragma unroll
    for (int ct = 0; ct < 8; ++ct) {
        v4f acc = {0.f, 0.f, 0.f, 0.f};
#pragma unroll
        for (int kc = 0; kc < 4; ++kc) {
            v8bf bw = *(const v8bf*)(ST + (size_t)(ct * 16 + c) * D_ + kc * 32 + q * 8);
            acc = __builtin_amdgcn_mfma_f32_16x16x32_bf16(ahf[kc], bw, acc, 0, 0, 0);
        }
#pragma unroll
        for (int r = 0; r < 4; ++r) pw[q * 4 + r][ct * 16 + c] = acc[r];
    }
    __builtin_amdgcn_wave_barrier();
    {
        int row = lane >> 2, seg = lane & 3;
#pragma unroll
        for (int v = 0; v < 4; ++v) {
            v8bf gv;
#pragma unroll
            for (int j = 0; j < 8; ++j) gv[j] = (bf16_t)pw[row][seg * 32 + v * 8 + j];
            *(v8bf*)(gb + (size_t)(nrow0 + row) * D_ + seg * 32 + v * 8) = gv;
        }
    }
}

// ---------------------------------------------------------------------------
// k_att v6: r4-v5 proven structure (wave-private, no block barriers, LDS
// transpose + full-line 16B Pt stores, bitmask adj), with the symmetry
// trick applied: E = g.h^T only -> HALF the MFMAs (16/t in 4 chains of 4),
// HALF the B-loads (4/t), HALF the persistent A-frags (64 VGPR, was 128).
// ---------------------------------------------------------------------------
__global__ __launch_bounds__(256, 2) void k_att(
    const bf16_t* __restrict__ hb, const bf16_t* __restrict__ gb,
    const unsigned int* __restrict__ mk, float* __restrict__ colsum,
    bf16_t* __restrict__ Pt)
{
    int bid = blockIdx.x;
    int b = bid & 7;
    int rest = bid >> 3;          // 0..255
    int nblk = rest >> 3;         // 0..31
    int mgrp = rest & 7;          // 0..7
    int wave = threadIdx.x >> 6;
    int lane = threadIdx.x & 63;
    int q = lane >> 4;
    int c = lane & 15;
    int nbase = nblk * 64;
    int mwav = mgrp * 256 + wave * 64;
    const size_t hgoff = (size_t)b * N_ * D_;
    const unsigned int* mkb = mk + (size_t)b * N_ * NW_;

    __shared__ bf16_t eb_all[4][64][72];
    bf16_t (*eb)[72] = eb_all[wave];

    // mask word-pairs covering this wave's 64-m window, per (sub, r) row
    uint2 wq[4][4];
#pragma unroll
    for (int sub = 0; sub < 4; ++sub)
#pragma unroll
        for (int r = 0; r < 4; ++r) {
            int row = nbase + sub * 16 + q * 4 + r;
            wq[sub][r] = *(const uint2*)(mkb + (size_t)row * NW_ + (mwav >> 5));
        }

    // A-frags: 4 n-subtiles of g only (64 VGPR persistent)
    v8bf ag[4][4];
#pragma unroll
    for (int sub = 0; sub < 4; ++sub)
#pragma unroll
        for (int kc = 0; kc < 4; ++kc)
            ag[sub][kc] = *(const v8bf*)(gb + hgoff
                + (size_t)(nbase + sub * 16 + c) * D_ + kc * 32 + q * 8);

#pragma unroll
    for (int t = 0; t < 4; ++t) {
        int mt = mwav + t * 16;
        // B-frags: 4 independent 16B loads (h rows m)
        v8bf bh[4];
#pragma unroll
        for (int kc = 0; kc < 4; ++kc)
            bh[kc] = *(const v8bf*)(hb + hgoff
                + (size_t)(mt + c) * D_ + kc * 32 + q * 8);
        v4f e[4];
#pragma unroll
        for (int sub = 0; sub < 4; ++sub) e[sub] = (v4f){0.f, 0.f, 0.f, 0.f};
#pragma unroll
        for (int kc = 0; kc < 4; ++kc)
#pragma unroll
            for (int sub = 0; sub < 4; ++sub)
                e[sub] = __builtin_amdgcn_mfma_f32_16x16x32_bf16(ag[sub][kc], bh[kc], e[sub], 0, 0, 0);
        unsigned int sh = (unsigned)((t & 1) * 16 + c);
        float cs = 0.f;
#pragma unroll
        for (int sub = 0; sub < 4; ++sub)
#pragma unroll
            for (int r = 0; r < 4; ++r) {
                unsigned int wv = (t >> 1) ? wq[sub][r].y : wq[sub][r].x;
                float ex = __expf(e[sub][r]);
                float pv = ((wv >> sh) & 1u) ? ex : 0.f;
                eb[sub * 16 + q * 4 + r][t * 16 + c] = (bf16_t)pv;
                cs += pv;
            }
        cs += __shfl_xor(cs, 16);
        cs += __shfl_xor(cs, 32);
        if (lane < 16) atomicAdd(&colsum[b * N_ + mt + lane], cs);
    }
    __builtin_amdgcn_wave_barrier();
    // 64n x 64m bf16 tile -> coalesced 16B stores (full 64B lines)
    int prow = lane >> 3, pseg = lane & 7;
#pragma unroll
    for (int pass = 0; pass < 8; ++pass) {
        int row = pass * 8 + prow;
        v8bf o = *(const v8bf*)&eb[row][pseg * 8];
        *(v8bf*)(Pt + ((size_t)b * N_ + nbase + row) * N_ + mwav + pseg * 8) = o;
    }
}

// ---------------------------------------------------------------------------
// k_scaleT: hbTs[b][d][m] = h[b][m][d] * inv(colsum[b][m]).
// ---------------------------------------------------------------------------
__global__ __launch_bounds__(256) void k_scaleT(
    const bf16_t* __restrict__ hb, const float* __restrict__ colsum,
    bf16_t* __restrict__ hbTs)
{
    int bid = blockIdx.x;
    int b = bid >> 6;
    int rem = bid & 63;
    int nblk = rem >> 1;
    int dblk = rem & 1;
    int tid = threadIdx.x;
    __shared__ bf16_t sm[64][72];
    __shared__ float sinv[64];
    int n0 = nblk * 64, d0 = dblk * 64;
    int r = tid >> 3, cg = tid & 7;
#pragma unroll
    for (int rr = 0; rr < 2; ++rr) {
        int row = r + rr * 32;
        *(v8bf*)&sm[row][cg * 8] =
            *(const v8bf*)(hb + (size_t)(b * N_ + n0 + row) * D_ + d0 + cg * 8);
    }
    if (tid < 64) {
        float s = colsum[b * N_ + n0 + tid];
        sinv[tid] = (s > 0.f) ? 1.f / s : 0.f;
    }
    __syncthreads();
#pragma unroll
    for (int rr = 0; rr < 2; ++rr) {
        int dr = r + rr * 32;
        v8bf v;
#pragma unroll
        for (int jj = 0; jj < 8; ++jj)
            v[jj] = (bf16_t)((float)sm[cg * 8 + jj][dr] * sinv[cg * 8 + jj]);
        *(v8bf*)(hbTs + (size_t)(b * D_ + d0 + dr) * N_ + n0 + cg * 8) = v;
    }
}

// ---------------------------------------------------------------------------
// k_out v4: ZERO-combine. h' = Pt @ hbTs + fused relu/gate epilogue.
// grid 512 (b x 64 nblk of 32n), 512 thr = 8 waves. Wave = (nsub 0..1,
// dq 0..3): owns a DISJOINT 16n x 32d output slice, reduces the FULL
// m=2048 itself (64 iters x {3 loads, 2 MFMAs}, all L2-resident).
// No inter-wave combine (r0's 8 serialized rounds, r2's LDS atomics both
// lost): ONE barrier total before the epilogue.
// ---------------------------------------------------------------------------
__global__ __launch_bounds__(512, 2) void k_out(
    const bf16_t* __restrict__ Pt, const bf16_t* __restrict__ hbTs,
    const float* __restrict__ x, const float* __restrict__ gw,
    const float* __restrict__ gbias, float* __restrict__ out)
{
    int bid = blockIdx.x;
    int b = bid & 7;
    int nblk = bid >> 3;          // 0..63
    int tid = threadIdx.x;
    int wave = tid >> 6;
    int lane = tid & 63;
    int q = lane >> 4;
    int c = lane & 15;
    int nbase = nblk * 32;
    int nsub = wave & 1;          // 16 n-rows
    int dq = wave >> 1;           // 32 d-cols

    __shared__ float hp[2][16][132];

    const bf16_t* hTb  = hbTs + (size_t)b * D_ * N_;
    const bf16_t* Arow = Pt + (size_t)b * N_ * N_ + (size_t)(nbase + nsub * 16 + c) * N_;
    const bf16_t* Br0  = hTb + (size_t)(dq * 32 + c) * N_;
    const bf16_t* Br1  = hTb + (size_t)(dq * 32 + 16 + c) * N_;

    v4f acc0 = {0.f, 0.f, 0.f, 0.f};
    v4f acc1 = {0.f, 0.f, 0.f, 0.f};
#pragma unroll 4
    for (int ch = 0; ch < 64; ++ch) {
        int mo = ch * 32 + q * 8;
        v8bf pa = *(const v8bf*)(Arow + mo);
        v8bf v0 = *(const v8bf*)(Br0 + mo);
        v8bf v1 = *(const v8bf*)(Br1 + mo);
        acc0 = __builtin_amdgcn_mfma_f32_16x16x32_bf16(pa, v0, acc0, 0, 0, 0);
        acc1 = __builtin_amdgcn_mfma_f32_16x16x32_bf16(pa, v1, acc1, 0, 0, 0);
    }

    // disjoint writes; one barrier total
#pragma unroll
    for (int r = 0; r < 4; ++r) {
        hp[nsub][q * 4 + r][dq * 32 + c]      = acc0[r];
        hp[nsub][q * 4 + r][dq * 32 + 16 + c] = acc1[r];
    }
    __syncthreads();

    // fused epilogue: 512 thr = 32 rows x 16 segs x 8 d
    int row = tid >> 4;           // 0..31
    int seg = tid & 15;           // d = seg*8
    size_t g = (size_t)b * N_ + nbase + row;
    const float* xr = x + g * D_ + seg * 8;
    float xv[8], hv[8];
    {
        float4 f0 = *(const float4*)(xr);
        float4 f1 = *(const float4*)(xr + 4);
        xv[0]=f0.x; xv[1]=f0.y; xv[2]=f0.z; xv[3]=f0.w;
        xv[4]=f1.x; xv[5]=f1.y; xv[6]=f1.z; xv[7]=f1.w;
    }
    const float* hrow = &hp[row >> 4][row & 15][seg * 8];
#pragma unroll
    for (int j = 0; j < 8; ++j) hv[j] = fmaxf(hrow[j], 0.f);
    float part = 0.f;
#pragma unroll
    for (int j = 0; j < 8; ++j)
        part += xv[j] * gw[seg * 8 + j] + hv[j] * gw[D_ + seg * 8 + j];
    part += __shfl_xor(part, 1);
    part += __shfl_xor(part, 2);
    part += __shfl_xor(part, 4);
    part += __shfl_xor(part, 8);
    float coeff = 1.f / (1.f + __expf(-(part + gbias[0])));
    float* orow = out + g * D_ + seg * 8;
    float4 o0, o1;
    o0.x = coeff * xv[0] + (1.f - coeff) * hv[0];
    o0.y = coeff * xv[1] + (1.f - coeff) * hv[1];
    o0.z = coeff * xv[2] + (1.f - coeff) * hv[2];
    o0.w = coeff * xv[3] + (1.f - coeff) * hv[3];
    o1.x = coeff * xv[4] + (1.f - coeff) * hv[4];
    o1.y = coeff * xv[5] + (1.f - coeff) * hv[5];
    o1.z = coeff * xv[6] + (1.f - coeff) * hv[6];
    o1.w = coeff * xv[7] + (1.f - coeff) * hv[7];
    *(float4*)(orow)     = o0;
    *(float4*)(orow + 4) = o1;
}

// ---------------------------------------------------------------------------
extern "C" void kernel_launch(void* const* d_in, const int* in_sizes, int n_in,
                              void* d_out, int out_size, void* d_ws, size_t ws_size,
                              hipStream_t stream)
{
    const float* x     = (const float*)d_in[0];
    const float* adj   = (const float*)d_in[1];
    const float* Ww    = (const float*)d_in[2];
    const float* Wb    = (const float*)d_in[3];
    const float* Aw    = (const float*)d_in[4];
    const float* gw    = (const float*)d_in[5];
    const float* gbias = (const float*)d_in[6];
    float* out = (float*)d_out;

    char* ws = (char*)d_ws;
    bf16_t* hb     = (bf16_t*)(ws);                          // 4 MB
    bf16_t* gb     = (bf16_t*)(ws + (4 << 20));              // 4 MB
    bf16_t* hbTs   = (bf16_t*)(ws + (8 << 20));              // 4 MB
    float*  colsum = (float*)(ws + (12 << 20));              // 64 KB
    unsigned int* mkw = (unsigned int*)(ws + (13 << 20));    // 4 MB
    bf16_t* Pt     = (bf16_t*)(ws + (17 << 20));             // 64 MB
    bf16_t* WT     = (bf16_t*)(ws + (81 << 20));             // 32 KB
    bf16_t* ST     = (bf16_t*)(ws + (81 << 20) + (32 << 10));// 32 KB

    hipMemsetAsync(colsum, 0, B_ * N_ * sizeof(float), stream);
    k_prep<<<64, 256, 0, stream>>>(Ww, Aw, WT, ST);
    k_mask<<<B_ * N_ * NW_ / 256, 256, 0, stream>>>(adj, mkw);
    k_hg<<<B_ * N_ / 64, 256, 0, stream>>>(x, Wb, WT, ST, hb, gb);
    k_att<<<2048, 256, 0, stream>>>(hb, gb, mkw, colsum, Pt);
    k_scaleT<<<512, 256, 0, stream>>>(hb, colsum, hbTs);
    k_out<<<512, 512, 0, stream>>>(Pt, hbTs, x, gw, gbias, out);
}

// Round 7
// 344.646 us; speedup vs baseline: 1.3044x; 1.0239x over previous
//
#include <hip/hip_runtime.h>
#include <hip/hip_bf16.h>

#define B_ 8
#define N_ 2048
#define D_ 128
#define NW_ (N_ / 32)   // mask words per row = 64

typedef __bf16 bf16_t;
typedef __bf16 v8bf __attribute__((ext_vector_type(8)));
typedef float  v4f  __attribute__((ext_vector_type(4)));

// ---------------------------------------------------------------------------
// k_prep: WT[o][i] = (bf16)Ww[i][o];  ST[o][i] = (bf16)(Aw[i][o]+Aw[o][i]).
// Symmetry trick: e + e^T = h A h^T + h A^T h^T = h (A+A^T) h^T, so with
// g = h@(A+A^T) the E-phase needs ONE product g.h^T instead of two.
// ---------------------------------------------------------------------------
__global__ __launch_bounds__(256) void k_prep(
    const float* __restrict__ Ww, const float* __restrict__ Aw,
    bf16_t* __restrict__ WT, bf16_t* __restrict__ ST)
{
    int idx = blockIdx.x * 256 + threadIdx.x;   // 0..16383
    int o = idx >> 7, i = idx & 127;
    WT[idx] = (bf16_t)Ww[i * D_ + o];
    ST[idx] = (bf16_t)(Aw[i * D_ + o] + Aw[o * D_ + i]);
}

// ---------------------------------------------------------------------------
// k_mask: pack adj>0 into bits. mk[b][n][m/32], bit (m&31). Exact (adj is
// {0.0,1.0}). Streams 134 MB once at dense BW.
// ---------------------------------------------------------------------------
__global__ __launch_bounds__(256) void k_mask(
    const float* __restrict__ adj, unsigned int* __restrict__ mk)
{
    int w = blockIdx.x * 256 + threadIdx.x;      // 0 .. 8*2048*64-1
    const float* src = adj + (size_t)w * 32;
    unsigned int bits = 0;
#pragma unroll
    for (int k = 0; k < 8; ++k) {
        float4 f = *(const float4*)(src + k * 4);
        bits |= (f.x > 0.f ? 1u : 0u) << (k * 4 + 0);
        bits |= (f.y > 0.f ? 1u : 0u) << (k * 4 + 1);
        bits |= (f.z > 0.f ? 1u : 0u) << (k * 4 + 2);
        bits |= (f.w > 0.f ? 1u : 0u) << (k * 4 + 3);
    }
    mk[w] = bits;
}

// ---------------------------------------------------------------------------
// k_hg (MFMA): h = x@W + b; g = h@S.  Block = 64 rows, 4 waves x 16 rows.
// ---------------------------------------------------------------------------
__global__ __launch_bounds__(256) void k_hg(
    const float* __restrict__ x, const float* __restrict__ Wb,
    const bf16_t* __restrict__ WT, const bf16_t* __restrict__ ST,
    bf16_t* __restrict__ hb, bf16_t* __restrict__ gb)
{
    int wave = threadIdx.x >> 6;
    int lane = threadIdx.x & 63;
    int q = lane >> 4;
    int c = lane & 15;
    int nrow0 = blockIdx.x * 64 + wave * 16;    // global flat row (b*N+n)

    __shared__ float pw_all[4][16][132];
    float (*pw)[132] = pw_all[wave];

    v8bf ax[4];
#pragma unroll
    for (int kc = 0; kc < 4; ++kc) {
        const float* src = x + (size_t)(nrow0 + c) * D_ + kc * 32 + q * 8;
        float4 f0 = *(const float4*)src;
        float4 f1 = *(const float4*)(src + 4);
        v8bf a;
        a[0]=(bf16_t)f0.x; a[1]=(bf16_t)f0.y; a[2]=(bf16_t)f0.z; a[3]=(bf16_t)f0.w;
        a[4]=(bf16_t)f1.x; a[5]=(bf16_t)f1.y; a[6]=(bf16_t)f1.z; a[7]=(bf16_t)f1.w;
        ax[kc] = a;
    }

#pragma unroll
    for (int ct = 0; ct < 8; ++ct) {
        float bias = Wb[ct * 16 + c];
        v4f acc = {bias, bias, bias, bias};
#pragma unroll
        for (int kc = 0; kc < 4; ++kc) {
            v8bf bw = *(const v8bf*)(WT + (size_t)(ct * 16 + c) * D_ + kc * 32 + q * 8);
            acc = __builtin_amdgcn_mfma_f32_16x16x32_bf16(ax[kc], bw, acc, 0, 0, 0);
        }
#pragma unroll
        for (int r = 0; r < 4; ++r) pw[q * 4 + r][ct * 16 + c] = acc[r];
    }
    __builtin_amdgcn_wave_barrier();

    v8bf ahf[4];
#pragma unroll
    for (int kc = 0; kc < 4; ++kc) {
        v4f p0 = *(const v4f*)&pw[c][kc * 32 + q * 8];
        v4f p1 = *(const v4f*)&pw[c][kc * 32 + q * 8 + 4];
        v8bf a;
#pragma unroll
        for (int j = 0; j < 4; ++j) { a[j] = (bf16_t)p0[j]; a[j+4] = (bf16_t)p1[j]; }
        ahf[kc] = a;
    }
    {
        int row = lane >> 2, seg = lane & 3;
#pragma unroll
        for (int v = 0; v < 4; ++v) {
            v8bf hv;
#pragma unroll
            for (int j = 0; j < 8; ++j) hv[j] = (bf16_t)pw[row][seg * 32 + v * 8 + j];
            *(v8bf*)(hb + (size_t)(nrow0 + row) * D_ + seg * 32 + v * 8) = hv;
        }
    }
    __builtin_amdgcn_wave_barrier();

#pragma unroll
    for (int ct = 0; ct < 8; ++ct) {
        v4f acc = {0.f, 0.f, 0.f, 0.f};
#pragma unroll
        for (int kc = 0; kc < 4; ++kc) {
            v8bf bw = *(const v8bf*)(ST + (size_t)(ct * 16 + c) * D_ + kc * 32 + q * 8);
            acc = __builtin_amdgcn_mfma_f32_16x16x32_bf16(ahf[kc], bw, acc, 0, 0, 0);
        }
#pragma unroll
        for (int r = 0; r < 4; ++r) pw[q * 4 + r][ct * 16 + c] = acc[r];
    }
    __builtin_amdgcn_wave_barrier();
    {
        int row = lane >> 2, seg = lane & 3;
#pragma unroll
        for (int v = 0; v < 4; ++v) {
            v8bf gv;
#pragma unroll
            for (int j = 0; j < 8; ++j) gv[j] = (bf16_t)pw[row][seg * 32 + v * 8 + j];
            *(v8bf*)(gb + (size_t)(nrow0 + row) * D_ + seg * 32 + v * 8) = gv;
        }
    }
}

// ---------------------------------------------------------------------------
// k_att v6 (unchanged from r6): wave-private, symmetry trick (E = g.h^T),
// bitmask adj, LDS transpose + full-line 16B Pt stores.
// ---------------------------------------------------------------------------
__global__ __launch_bounds__(256, 2) void k_att(
    const bf16_t* __restrict__ hb, const bf16_t* __restrict__ gb,
    const unsigned int* __restrict__ mk, float* __restrict__ colsum,
    bf16_t* __restrict__ Pt)
{
    int bid = blockIdx.x;
    int b = bid & 7;
    int rest = bid >> 3;          // 0..255
    int nblk = rest >> 3;         // 0..31
    int mgrp = rest & 7;          // 0..7
    int wave = threadIdx.x >> 6;
    int lane = threadIdx.x & 63;
    int q = lane >> 4;
    int c = lane & 15;
    int nbase = nblk * 64;
    int mwav = mgrp * 256 + wave * 64;
    const size_t hgoff = (size_t)b * N_ * D_;
    const unsigned int* mkb = mk + (size_t)b * N_ * NW_;

    __shared__ bf16_t eb_all[4][64][72];
    bf16_t (*eb)[72] = eb_all[wave];

    // mask word-pairs covering this wave's 64-m window, per (sub, r) row
    uint2 wq[4][4];
#pragma unroll
    for (int sub = 0; sub < 4; ++sub)
#pragma unroll
        for (int r = 0; r < 4; ++r) {
            int row = nbase + sub * 16 + q * 4 + r;
            wq[sub][r] = *(const uint2*)(mkb + (size_t)row * NW_ + (mwav >> 5));
        }

    // A-frags: 4 n-subtiles of g only (64 VGPR persistent)
    v8bf ag[4][4];
#pragma unroll
    for (int sub = 0; sub < 4; ++sub)
#pragma unroll
        for (int kc = 0; kc < 4; ++kc)
            ag[sub][kc] = *(const v8bf*)(gb + hgoff
                + (size_t)(nbase + sub * 16 + c) * D_ + kc * 32 + q * 8);

#pragma unroll
    for (int t = 0; t < 4; ++t) {
        int mt = mwav + t * 16;
        // B-frags: 4 independent 16B loads (h rows m)
        v8bf bh[4];
#pragma unroll
        for (int kc = 0; kc < 4; ++kc)
            bh[kc] = *(const v8bf*)(hb + hgoff
                + (size_t)(mt + c) * D_ + kc * 32 + q * 8);
        v4f e[4];
#pragma unroll
        for (int sub = 0; sub < 4; ++sub) e[sub] = (v4f){0.f, 0.f, 0.f, 0.f};
#pragma unroll
        for (int kc = 0; kc < 4; ++kc)
#pragma unroll
            for (int sub = 0; sub < 4; ++sub)
                e[sub] = __builtin_amdgcn_mfma_f32_16x16x32_bf16(ag[sub][kc], bh[kc], e[sub], 0, 0, 0);
        unsigned int sh = (unsigned)((t & 1) * 16 + c);
        float cs = 0.f;
#pragma unroll
        for (int sub = 0; sub < 4; ++sub)
#pragma unroll
            for (int r = 0; r < 4; ++r) {
                unsigned int wv = (t >> 1) ? wq[sub][r].y : wq[sub][r].x;
                float ex = __expf(e[sub][r]);
                float pv = ((wv >> sh) & 1u) ? ex : 0.f;
                eb[sub * 16 + q * 4 + r][t * 16 + c] = (bf16_t)pv;
                cs += pv;
            }
        cs += __shfl_xor(cs, 16);
        cs += __shfl_xor(cs, 32);
        if (lane < 16) atomicAdd(&colsum[b * N_ + mt + lane], cs);
    }
    __builtin_amdgcn_wave_barrier();
    // 64n x 64m bf16 tile -> coalesced 16B stores (full 64B lines)
    int prow = lane >> 3, pseg = lane & 7;
#pragma unroll
    for (int pass = 0; pass < 8; ++pass) {
        int row = pass * 8 + prow;
        v8bf o = *(const v8bf*)&eb[row][pseg * 8];
        *(v8bf*)(Pt + ((size_t)b * N_ + nbase + row) * N_ + mwav + pseg * 8) = o;
    }
}

// ---------------------------------------------------------------------------
// k_scaleT: hbTs[b][d][m] = h[b][m][d] * inv(colsum[b][m]).
// ---------------------------------------------------------------------------
__global__ __launch_bounds__(256) void k_scaleT(
    const bf16_t* __restrict__ hb, const float* __restrict__ colsum,
    bf16_t* __restrict__ hbTs)
{
    int bid = blockIdx.x;
    int b = bid >> 6;
    int rem = bid & 63;
    int nblk = rem >> 1;
    int dblk = rem & 1;
    int tid = threadIdx.x;
    __shared__ bf16_t sm[64][72];
    __shared__ float sinv[64];
    int n0 = nblk * 64, d0 = dblk * 64;
    int r = tid >> 3, cg = tid & 7;
#pragma unroll
    for (int rr = 0; rr < 2; ++rr) {
        int row = r + rr * 32;
        *(v8bf*)&sm[row][cg * 8] =
            *(const v8bf*)(hb + (size_t)(b * N_ + n0 + row) * D_ + d0 + cg * 8);
    }
    if (tid < 64) {
        float s = colsum[b * N_ + n0 + tid];
        sinv[tid] = (s > 0.f) ? 1.f / s : 0.f;
    }
    __syncthreads();
#pragma unroll
    for (int rr = 0; rr < 2; ++rr) {
        int dr = r + rr * 32;
        v8bf v;
#pragma unroll
        for (int jj = 0; jj < 8; ++jj)
            v[jj] = (bf16_t)((float)sm[cg * 8 + jj][dr] * sinv[cg * 8 + jj]);
        *(v8bf*)(hbTs + (size_t)(b * D_ + d0 + dr) * N_ + n0 + cg * 8) = v;
    }
}

// ---------------------------------------------------------------------------
// k_out v5: zero-combine + FAT waves. grid 256 (b=bid&7 -> XCD-locked batch:
// 512 KB hbTs slab L2-resident per XCD). 512 thr = 8 waves = 4 nsub x 2 dh;
// wave owns a DISJOINT 16n x 64d slice, reduces the full m=2048 itself.
// Per 32-m chunk: 1 A-load (shared by 2 waves) + 4 B-loads (shared by 4
// waves) -> 4 MFMAs in 4 independent chains; unroll 2 => 10 loads / 8 MFMAs
// in flight. launch_bounds(512,1): grid=1 block/CU anyway, so don't cap
// VGPR (r6's (512,2)-style thinness gave VGPR=24 = no pipelining = 91 us).
// ONE barrier total before the fused epilogue.
// ---------------------------------------------------------------------------
__global__ __launch_bounds__(512, 1) void k_out(
    const bf16_t* __restrict__ Pt, const bf16_t* __restrict__ hbTs,
    const float* __restrict__ x, const float* __restrict__ gw,
    const float* __restrict__ gbias, float* __restrict__ out)
{
    int bid = blockIdx.x;
    int b = bid & 7;
    int nblk = bid >> 3;          // 0..31
    int tid = threadIdx.x;
    int wave = tid >> 6;
    int lane = tid & 63;
    int q = lane >> 4;
    int c = lane & 15;
    int nbase = nblk * 64;
    int nsub = wave & 3;          // 16 n-rows
    int dh = wave >> 2;           // 64 d-cols

    __shared__ float hp[64][132];

    const bf16_t* hTb  = hbTs + (size_t)b * D_ * N_;
    const bf16_t* Arow = Pt + (size_t)b * N_ * N_ + (size_t)(nbase + nsub * 16 + c) * N_;
    const bf16_t* Br[4];
#pragma unroll
    for (int dt = 0; dt < 4; ++dt)
        Br[dt] = hTb + (size_t)(dh * 64 + dt * 16 + c) * N_;

    v4f acc[4];
#pragma unroll
    for (int dt = 0; dt < 4; ++dt) acc[dt] = (v4f){0.f, 0.f, 0.f, 0.f};

#pragma unroll 2
    for (int ch = 0; ch < 64; ++ch) {
        int mo = ch * 32 + q * 8;
        v8bf pa = *(const v8bf*)(Arow + mo);
        v8bf vt[4];
#pragma unroll
        for (int dt = 0; dt < 4; ++dt)
            vt[dt] = *(const v8bf*)(Br[dt] + mo);
#pragma unroll
        for (int dt = 0; dt < 4; ++dt)
            acc[dt] = __builtin_amdgcn_mfma_f32_16x16x32_bf16(pa, vt[dt], acc[dt], 0, 0, 0);
    }

    // disjoint writes; one barrier total
#pragma unroll
    for (int dt = 0; dt < 4; ++dt)
#pragma unroll
        for (int r = 0; r < 4; ++r)
            hp[nsub * 16 + q * 4 + r][dh * 64 + dt * 16 + c] = acc[dt][r];
    __syncthreads();

    // fused epilogue: 512 thr = 64 rows x 8 segs x 16 d
    int row = tid >> 3;
    int seg = tid & 7;
    size_t g = (size_t)b * N_ + nbase + row;
    const float* xr = x + g * D_ + seg * 16;
    float xv[16], hv[16];
#pragma unroll
    for (int j = 0; j < 16; j += 4) {
        float4 f = *(const float4*)(xr + j);
        xv[j] = f.x; xv[j+1] = f.y; xv[j+2] = f.z; xv[j+3] = f.w;
    }
#pragma unroll
    for (int j = 0; j < 16; ++j) hv[j] = fmaxf(hp[row][seg * 16 + j], 0.f);
    float part = 0.f;
#pragma unroll
    for (int j = 0; j < 16; ++j)
        part += xv[j] * gw[seg * 16 + j] + hv[j] * gw[D_ + seg * 16 + j];
    part += __shfl_xor(part, 1);
    part += __shfl_xor(part, 2);
    part += __shfl_xor(part, 4);
    float coeff = 1.f / (1.f + __expf(-(part + gbias[0])));
    float* orow = out + g * D_ + seg * 16;
#pragma unroll
    for (int j = 0; j < 16; j += 4) {
        float4 o;
        o.x = coeff * xv[j]   + (1.f - coeff) * hv[j];
        o.y = coeff * xv[j+1] + (1.f - coeff) * hv[j+1];
        o.z = coeff * xv[j+2] + (1.f - coeff) * hv[j+2];
        o.w = coeff * xv[j+3] + (1.f - coeff) * hv[j+3];
        *(float4*)(orow + j) = o;
    }
}

// ---------------------------------------------------------------------------
extern "C" void kernel_launch(void* const* d_in, const int* in_sizes, int n_in,
                              void* d_out, int out_size, void* d_ws, size_t ws_size,
                              hipStream_t stream)
{
    const float* x     = (const float*)d_in[0];
    const float* adj   = (const float*)d_in[1];
    const float* Ww    = (const float*)d_in[2];
    const float* Wb    = (const float*)d_in[3];
    const float* Aw    = (const float*)d_in[4];
    const float* gw    = (const float*)d_in[5];
    const float* gbias = (const float*)d_in[6];
    float* out = (float*)d_out;

    char* ws = (char*)d_ws;
    bf16_t* hb     = (bf16_t*)(ws);                          // 4 MB
    bf16_t* gb     = (bf16_t*)(ws + (4 << 20));              // 4 MB
    bf16_t* hbTs   = (bf16_t*)(ws + (8 << 20));              // 4 MB
    float*  colsum = (float*)(ws + (12 << 20));              // 64 KB
    unsigned int* mkw = (unsigned int*)(ws + (13 << 20));    // 4 MB
    bf16_t* Pt     = (bf16_t*)(ws + (17 << 20));             // 64 MB
    bf16_t* WT     = (bf16_t*)(ws + (81 << 20));             // 32 KB
    bf16_t* ST     = (bf16_t*)(ws + (81 << 20) + (32 << 10));// 32 KB

    hipMemsetAsync(colsum, 0, B_ * N_ * sizeof(float), stream);
    k_prep<<<64, 256, 0, stream>>>(Ww, Aw, WT, ST);
    k_mask<<<B_ * N_ * NW_ / 256, 256, 0, stream>>>(adj, mkw);
    k_hg<<<B_ * N_ / 64, 256, 0, stream>>>(x, Wb, WT, ST, hb, gb);
    k_att<<<2048, 256, 0, stream>>>(hb, gb, mkw, colsum, Pt);
    k_scaleT<<<512, 256, 0, stream>>>(hb, colsum, hbTs);
    k_out<<<256, 512, 0, stream>>>(Pt, hbTs, x, gw, gbias, out);
}